// Round 1
// baseline (1227.122 us; speedup 1.0000x reference)
//
#include <hip/hip_runtime.h>
#include <math.h>

#define BB 8
#define CC 512
#define TT 1500
#define KK 4096
#define NN (BB*TT)   // 12000

#define NEG_HUGE -3.0e38f

// online-softmax state combine: (m,s) <- combine((m,s),(m2,s2))
__device__ __forceinline__ void smx_combine(float& m, float& s, float m2, float s2){
  if (m2 > m) { s = s*__expf(m - m2) + s2; m = m2; }
  else        { s = s + s2*__expf(m2 - m); }
}

// ---- codebook transpose: cbT[c*K + k] = cb[k*C + c] ----
__global__ __launch_bounds__(256) void k_transpose(const float* __restrict__ src, float* __restrict__ dst){
  __shared__ float tile[64][65];
  int kb = blockIdx.x*64, cb0 = blockIdx.y*64;
  for (int e = threadIdx.x; e < 64*64; e += 256){
    int kk = e >> 6, cc = e & 63;
    tile[kk][cc] = src[(size_t)(kb+kk)*CC + cb0 + cc];
  }
  __syncthreads();
  for (int e = threadIdx.x; e < 64*64; e += 256){
    int cc = e >> 6, kk = e & 63;
    dst[(size_t)(cb0+cc)*KK + kb + kk] = tile[kk][cc];
  }
}

// ---- per-code squared norms ----
__global__ __launch_bounds__(256) void k_c2(const float* __restrict__ cb, float* __restrict__ c2){
  int k = blockIdx.x*4 + (threadIdx.x >> 6);
  int lane = threadIdx.x & 63;
  const float4* p = (const float4*)(cb + (size_t)k*CC);
  float s = 0.f;
  for (int i = lane; i < CC/4; i += 64){
    float4 v = p[i];
    s += v.x*v.x + v.y*v.y + v.z*v.z + v.w*v.w;
  }
  for (int off=1; off<64; off<<=1) s += __shfl_xor(s, off);
  if (lane == 0) c2[k] = s;
}

// ---- fused distance GEMM: per row, argmax(2*dot - c2) excl tgt, logsumexp, logit[tgt] ----
__global__ __launch_bounds__(256) void k_dist(const float* __restrict__ student,
    const int* __restrict__ codes, const float* __restrict__ cbT, const float* __restrict__ c2,
    int* __restrict__ hard_idx, float* __restrict__ accs){
  __shared__ float zs[CC][16];        // [c][row] 32KB
  __shared__ float red[4][8][5];
  int n0 = blockIdx.x * 16;
  int tid = threadIdx.x;
  for (int e = tid; e < CC*16; e += 256){
    int r = e & 15, c = e >> 4;
    int n = n0 + r, b = n / TT, t = n - b*TT;
    zs[c][r] = student[((size_t)b*CC + c)*TT + t];
  }
  __syncthreads();
  int g = tid >> 7;      // group: rows g*8..g*8+7
  int l = tid & 127;
  float m[8], ssum[8], bestv[8], ltgt[8];
  int besti[8], tgt[8];
#pragma unroll
  for (int r = 0; r < 8; ++r){
    m[r]=NEG_HUGE; ssum[r]=0.f; bestv[r]=NEG_HUGE; ltgt[r]=NEG_HUGE; besti[r]=0;
    tgt[r] = codes[n0 + g*8 + r];
  }
  for (int pass = 0; pass < 8; ++pass){
    int kb = pass*512 + l*4;
    float acc[8][4];
#pragma unroll
    for (int r=0;r<8;++r)
#pragma unroll
      for (int j=0;j<4;++j) acc[r][j]=0.f;
    for (int c = 0; c < CC; ++c){
      float4 cbv = *(const float4*)(cbT + (size_t)c*KK + kb);
      float4 za = *(const float4*)(&zs[c][g*8]);
      float4 zb = *(const float4*)(&zs[c][g*8+4]);
      float zr[8] = {za.x,za.y,za.z,za.w,zb.x,zb.y,zb.z,zb.w};
      float cj[4] = {cbv.x,cbv.y,cbv.z,cbv.w};
#pragma unroll
      for (int r=0;r<8;++r)
#pragma unroll
        for (int j=0;j<4;++j) acc[r][j] = fmaf(zr[r], cj[j], acc[r][j]);
    }
    float4 c2v4 = *(const float4*)(c2 + kb);
    float c2v[4] = {c2v4.x, c2v4.y, c2v4.z, c2v4.w};
#pragma unroll
    for (int r=0;r<8;++r){
#pragma unroll
      for (int j=0;j<4;++j){
        int kk2 = kb + j;
        float logit = (2.f*acc[r][j] - c2v[j]) * 10.f;   // /CE_TEMP
        if (kk2 == tgt[r]) ltgt[r] = logit;
        else if (logit > bestv[r]) { bestv[r] = logit; besti[r] = kk2; }
        smx_combine(m[r], ssum[r], logit, 1.f);
      }
    }
  }
  // 64-lane wave reduce
  for (int off = 1; off < 64; off <<= 1){
#pragma unroll
    for (int r = 0; r < 8; ++r){
      float m2 = __shfl_xor(m[r], off);
      float s2 = __shfl_xor(ssum[r], off);
      smx_combine(m[r], ssum[r], m2, s2);
      float b2 = __shfl_xor(bestv[r], off);
      int  bi2 = __shfl_xor(besti[r], off);
      if (b2 > bestv[r] || (b2 == bestv[r] && bi2 < besti[r])) { bestv[r]=b2; besti[r]=bi2; }
      float lt2 = __shfl_xor(ltgt[r], off);
      ltgt[r] = fmaxf(ltgt[r], lt2);
    }
  }
  int wave = tid >> 6;
  if ((tid & 63) == 0){
#pragma unroll
    for (int r = 0; r < 8; ++r){
      red[wave][r][0]=m[r]; red[wave][r][1]=ssum[r]; red[wave][r][2]=bestv[r];
      red[wave][r][3]=__int_as_float(besti[r]); red[wave][r][4]=ltgt[r];
    }
  }
  __syncthreads();
  if (tid < 16){
    int g2 = tid >> 3, r = tid & 7;
    int w0 = g2*2, w1 = w0+1;
    float M = red[w0][r][0], S = red[w0][r][1];
    smx_combine(M, S, red[w1][r][0], red[w1][r][1]);
    float bv = red[w0][r][2];  int bi  = __float_as_int(red[w0][r][3]);
    float bv1 = red[w1][r][2]; int bi1 = __float_as_int(red[w1][r][3]);
    if (bv1 > bv || (bv1 == bv && bi1 < bi)) { bv=bv1; bi=bi1; }
    float lt = fmaxf(red[w0][r][4], red[w1][r][4]);
    hard_idx[n0 + tid] = bi;
    atomicAdd(&accs[4], (M + logf(S)) - lt);   // ce contribution
  }
}

// ---- finalize: one pass over big tensors, per-row triplet + direction terms ----
__global__ __launch_bounds__(256) void k_final(const float* __restrict__ student, const float* __restrict__ teacher,
    const float* __restrict__ orig, const float* __restrict__ cb, const int* __restrict__ hard_idx,
    float* __restrict__ accs){
  __shared__ float red[5][4][64];
  int tt = threadIdx.x & 63, cg = threadIdx.x >> 6;
  int n = blockIdx.x*64 + tt;
  float dp2=0,dn2=0,mm=0,dd=0,md=0;
  if (n < NN){
    int b = n / TT, t = n - b*TT;
    size_t base = (size_t)b*CC*TT + t;
    const float* cbr = cb + (size_t)hard_idx[n]*CC;
    for (int c = cg*128; c < cg*128+128; ++c){
      float sv = student[base + (size_t)c*TT];
      float tv = teacher[base + (size_t)c*TT];
      float ov = orig[base + (size_t)c*TT];
      float cv = cbr[c];
      float u = sv - tv; dp2 = fmaf(u,u,dp2);
      float v = tv - cv; dn2 = fmaf(v,v,dn2);
      float mv = sv - ov, dv = tv - ov;
      mm = fmaf(mv,mv,mm); dd = fmaf(dv,dv,dd); md = fmaf(mv,dv,md);
    }
  }
  red[0][cg][tt]=dp2; red[1][cg][tt]=dn2; red[2][cg][tt]=mm; red[3][cg][tt]=dd; red[4][cg][tt]=md;
  __syncthreads();
  if (cg == 0){
    dp2 = red[0][0][tt]+red[0][1][tt]+red[0][2][tt]+red[0][3][tt];
    dn2 = red[1][0][tt]+red[1][1][tt]+red[1][2][tt]+red[1][3][tt];
    mm  = red[2][0][tt]+red[2][1][tt]+red[2][2][tt]+red[2][3][tt];
    dd  = red[3][0][tt]+red[3][1][tt]+red[3][2][tt]+red[3][3][tt];
    md  = red[4][0][tt]+red[4][1][tt]+red[4][2][tt]+red[4][3][tt];
    float trip=0.f, dc=0.f, nv=0.f;
    if (n < NN){
      float dpos = sqrtf(dp2), dneg = sqrtf(dn2);
      trip = fmaxf(dpos - dneg + 0.5f, 0.f);
      float mn = sqrtf(mm), dnn = sqrtf(dd);
      bool valid = (mn > 1e-6f) && (dnn > 1e-6f);
      float cosv = md / ((mn + 1e-8f)*(dnn + 1e-8f));
      if (valid){ dc = 1.f - cosv; nv = 1.f; }
    }
    for (int off=1; off<64; off<<=1){
      trip += __shfl_xor(trip,off);
      dc   += __shfl_xor(dc,off);
      nv   += __shfl_xor(nv,off);
      dp2  += __shfl_xor(dp2,off);
    }
    if (tt==0){
      atomicAdd(&accs[0],trip); atomicAdd(&accs[1],dc);
      atomicAdd(&accs[2],nv);   atomicAdd(&accs[3],dp2);
    }
  }
}

__global__ void k_total(const float* __restrict__ accs, float* __restrict__ out){
  float feat = accs[3] / (float)((size_t)BB*CC*TT);
  float trip = accs[0] / (float)NN;
  float ce   = accs[4] / (float)NN;
  float nv   = accs[2] < 1.f ? 1.f : accs[2];
  float dc   = accs[1] / nv;
  // total = feat + trip + ce + (feat + dc)
  out[0] = 2.f*feat + trip + ce + dc;
}

extern "C" void kernel_launch(void* const* d_in, const int* in_sizes, int n_in,
                              void* d_out, int out_size, void* d_ws, size_t ws_size,
                              hipStream_t stream){
  const float* student = (const float*)d_in[0];
  const float* teacher = (const float*)d_in[1];
  const float* cb      = (const float*)d_in[2];
  const int*   codes   = (const int*)d_in[3];
  const float* orig    = (const float*)d_in[4];

  float* ws   = (float*)d_ws;
  float* cbT  = ws;                          // C*K floats (8 MB)
  float* c2   = cbT + (size_t)CC*KK;         // K floats
  int*   hard = (int*)(c2 + KK);             // N ints
  float* accs = (float*)(hard + NN);         // 8 floats: [0]=trip [1]=dircos [2]=nvalid [3]=featsum [4]=ce

  hipMemsetAsync(accs, 0, 8*sizeof(float), stream);
  k_transpose<<<dim3(KK/64, CC/64), 256, 0, stream>>>(cb, cbT);
  k_c2<<<KK/4, 256, 0, stream>>>(cb, c2);
  k_dist<<<NN/16, 256, 0, stream>>>(student, codes, cbT, c2, hard, accs);
  k_final<<<(NN+63)/64, 256, 0, stream>>>(student, teacher, orig, cb, hard, accs);
  k_total<<<1, 1, 0, stream>>>(accs, (float*)d_out);
}

// Round 2
// 437.899 us; speedup vs baseline: 2.8023x; 2.8023x over previous
//
#include <hip/hip_runtime.h>
#include <math.h>

#define NN 12000
#define CCD 512
#define KK 4096
#define TT 1500
#define S20F 28.853900817779268f   // 20*log2(e)
#define SC2F 14.426950408889634f   // 10*log2(e)
#define LN2F 0.6931471805599453f

typedef float f32x4 __attribute__((ext_vector_type(4)));
typedef __bf16 bf16x8 __attribute__((ext_vector_type(8)));

__device__ __forceinline__ ushort f2bf(float f){
  uint u = __float_as_uint(f);
  uint r = (u + 0x7fffu + ((u >> 16) & 1u)) >> 16;
  return (ushort)r;
}
__device__ __forceinline__ float bf2f(ushort u){
  return __uint_as_float(((uint)u) << 16);
}

// ---- student (B,C,T) f32 -> zbf[N][C] bf16 (tiled transpose) ----
__global__ __launch_bounds__(256) void k_prep_z(const float* __restrict__ src, ushort* __restrict__ dst){
  __shared__ float tile[64][65];
  int b = blockIdx.z, c0 = blockIdx.y*64, t0 = blockIdx.x*64;
  const float* sb = src + ((size_t)b*CCD + c0)*TT + t0;
  for (int i = 0; i < 16; ++i){
    int e = i*256 + threadIdx.x;
    int cl = e >> 6, tl = e & 63;
    if (t0 + tl < TT) tile[cl][tl] = sb[(size_t)cl*TT + tl];
  }
  __syncthreads();
  for (int i = 0; i < 16; ++i){
    int e = i*256 + threadIdx.x;
    int tl = e >> 6, cl = e & 63;
    if (t0 + tl < TT) dst[((size_t)b*TT + t0 + tl)*CCD + c0 + cl] = f2bf(tile[cl][tl]);
  }
}

// ---- codebook f32 -> bf16 ----
__global__ __launch_bounds__(256) void k_prep_cb(const float* __restrict__ cb, ushort* __restrict__ dst){
  size_t idx = ((size_t)blockIdx.x*256 + threadIdx.x)*8;
  float4 v0 = *(const float4*)(cb + idx);
  float4 v1 = *(const float4*)(cb + idx + 4);
  uint4 o;
  o.x = (uint)f2bf(v0.x) | ((uint)f2bf(v0.y) << 16);
  o.y = (uint)f2bf(v0.z) | ((uint)f2bf(v0.w) << 16);
  o.z = (uint)f2bf(v1.x) | ((uint)f2bf(v1.y) << 16);
  o.w = (uint)f2bf(v1.z) | ((uint)f2bf(v1.w) << 16);
  *(uint4*)(dst + idx) = o;
}

// ---- per-code scaled squared norms: c2s[k] = ||c_k||^2 * 10*log2e ----
__global__ __launch_bounds__(256) void k_c2(const float* __restrict__ cb, float* __restrict__ c2s){
  int k = blockIdx.x*4 + (threadIdx.x >> 6);
  int lane = threadIdx.x & 63;
  const float4* p = (const float4*)(cb + (size_t)k*CCD);
  float s = 0.f;
  for (int i = lane; i < CCD/4; i += 64){
    float4 v = p[i];
    s += v.x*v.x + v.y*v.y + v.z*v.z + v.w*v.w;
  }
  for (int off=1; off<64; off<<=1) s += __shfl_xor(s, off);
  if (lane == 0) c2s[k] = s * SC2F;
}

// ---- fused bf16-MFMA distance GEMM with online softmax + argmax epilogue ----
// grid (125, 4): x = row block (96 rows), y = k-split (1024 codes each)
__global__ __launch_bounds__(256, 2) void k_dist(const ushort* __restrict__ zbf,
    const ushort* __restrict__ cbbf, const float* __restrict__ c2s,
    float4* __restrict__ pstate){
  __shared__ ushort cs[128*128];   // 32 KB, XOR-swizzled [code][c-chunk]
  int tid = threadIdx.x, w = tid >> 6, l = tid & 63;
  int lm = l & 15, k16 = l >> 4;
  int n0 = blockIdx.x*96, kb = blockIdx.y*1024;
  int wr0 = (w >> 1)*48, wc0 = (w & 1)*64;
  const ushort* ar[3];
#pragma unroll
  for (int fi=0; fi<3; ++fi) ar[fi] = zbf + (size_t)(n0 + wr0 + fi*16 + lm)*CCD;

  float m2[12], ss[12], bv[12]; int bi[12];
#pragma unroll
  for (int i=0;i<12;++i){ m2[i]=-3.0e38f; ss[i]=0.f; bv[i]=-3.0e38f; bi[i]=0; }

  for (int it = 0; it < 8; ++it){
    int kt = kb + it*128;
    int colg[4]; float c2r[4];
#pragma unroll
    for (int fj=0; fj<4; ++fj){ colg[fj] = kt + wc0 + fj*16 + lm; c2r[fj] = c2s[colg[fj]]; }
    f32x4 acc[3][4];
#pragma unroll
    for (int fi=0; fi<3; ++fi)
#pragma unroll
      for (int fj=0; fj<4; ++fj){ acc[fi][fj][0]=0.f; acc[fi][fj][1]=0.f; acc[fi][fj][2]=0.f; acc[fi][fj][3]=0.f; }

    for (int cc = 0; cc < 4; ++cc){
      // stage 128 codes x 128 c bf16 into LDS (swizzled)
#pragma unroll
      for (int i = 0; i < 8; ++i){
        int e = i*256 + tid, code = e >> 4, g = e & 15;
        uint4 v = *(const uint4*)(cbbf + (size_t)(kt+code)*CCD + cc*128 + g*8);
        *(uint4*)((char*)cs + code*256 + (((g ^ (code & 7)) << 4))) = v;
      }
      __syncthreads();
#pragma unroll
      for (int ks = 0; ks < 4; ++ks){
        bf16x8 a[3], b[4];
#pragma unroll
        for (int fi=0; fi<3; ++fi)
          a[fi] = *(const bf16x8*)(ar[fi] + cc*128 + ks*32 + k16*8);
#pragma unroll
        for (int fj=0; fj<4; ++fj){
          int code = wc0 + fj*16 + lm;
          int L = code*256 + ks*64 + k16*16;
          b[fj] = *(const bf16x8*)((char*)cs + (L ^ ((code & 7) << 4)));
        }
#pragma unroll
        for (int fi=0; fi<3; ++fi)
#pragma unroll
          for (int fj=0; fj<4; ++fj)
            acc[fi][fj] = __builtin_amdgcn_mfma_f32_16x16x32_bf16(a[fi], b[fj], acc[fi][fj], 0, 0, 0);
      }
      __syncthreads();
    }
    // epilogue: per-row (per lane: 12 rows) online softmax + argmax over the 4 cols
#pragma unroll
    for (int fi=0; fi<3; ++fi)
#pragma unroll
      for (int r=0; r<4; ++r){
        int i12 = fi*4 + r;
        float l2[4];
#pragma unroll
        for (int fj=0; fj<4; ++fj) l2[fj] = fmaf(acc[fi][fj][r], S20F, -c2r[fj]);
        float tm = fmaxf(fmaxf(l2[0], l2[1]), fmaxf(l2[2], l2[3]));
        float mn = fmaxf(m2[i12], tm);
        ss[i12] *= exp2f(m2[i12] - mn);
#pragma unroll
        for (int fj=0; fj<4; ++fj) ss[i12] += exp2f(l2[fj] - mn);
        m2[i12] = mn;
#pragma unroll
        for (int fj=0; fj<4; ++fj){
          if (l2[fj] > bv[i12]){ bv[i12] = l2[fj]; bi[i12] = colg[fj]; }
        }
      }
  }
  // butterfly across the 16 lanes sharing each row (xor within l&15)
#pragma unroll
  for (int off = 1; off < 16; off <<= 1){
#pragma unroll
    for (int i=0; i<12; ++i){
      float mo = __shfl_xor(m2[i], off), so = __shfl_xor(ss[i], off);
      float mn = fmaxf(m2[i], mo);
      ss[i] = ss[i]*exp2f(m2[i]-mn) + so*exp2f(mo-mn);
      m2[i] = mn;
      float bvo = __shfl_xor(bv[i], off); int bio = __shfl_xor(bi[i], off);
      if (bvo > bv[i] || (bvo == bv[i] && bio < bi[i])){ bv[i]=bvo; bi[i]=bio; }
    }
  }
  // combine column-wave pairs (w,w+1) via LDS scratch, then write partials
  float* scr = (float*)cs;
  if ((w & 1) && lm == 0){
#pragma unroll
    for (int fi=0; fi<3; ++fi)
#pragma unroll
      for (int r=0; r<4; ++r){
        int rl = fi*16 + k16*4 + r, o = ((w>>1)*48 + rl)*4, i12 = fi*4+r;
        scr[o]=m2[i12]; scr[o+1]=ss[i12]; scr[o+2]=bv[i12]; scr[o+3]=__int_as_float(bi[i12]);
      }
  }
  __syncthreads();
  if (!(w & 1) && lm == 0){
#pragma unroll
    for (int fi=0; fi<3; ++fi)
#pragma unroll
      for (int r=0; r<4; ++r){
        int rl = fi*16 + k16*4 + r, o = ((w>>1)*48 + rl)*4, i12 = fi*4+r;
        float mo=scr[o], so=scr[o+1], bvo=scr[o+2]; int bio=__float_as_int(scr[o+3]);
        float mn = fmaxf(m2[i12], mo);
        float s = ss[i12]*exp2f(m2[i12]-mn) + so*exp2f(mo-mn);
        float bvf = bv[i12]; int bif = bi[i12];
        if (bvo > bvf || (bvo == bvf && bio < bif)){ bvf=bvo; bif=bio; }
        int n = n0 + (w>>1)*48 + rl;
        pstate[(size_t)blockIdx.y*NN + n] = make_float4(mn, s, bvf, __int_as_float(bif));
      }
  }
}

// ---- merge the 4 k-splits per row ----
__global__ __launch_bounds__(256) void k_merge(const float4* __restrict__ pstate,
    const int* __restrict__ codes, float* __restrict__ lse2, int* __restrict__ hard,
    int* __restrict__ fixlist, int* __restrict__ fixcnt){
  int n = blockIdx.x*256 + threadIdx.x;
  if (n >= NN) return;
  float m=-3.0e38f, s=0.f, bv=-3.0e38f; int bi=0;
  for (int sp = 0; sp < 4; ++sp){
    float4 p = pstate[(size_t)sp*NN + n];
    float mn = fmaxf(m, p.x);
    s = s*exp2f(m-mn) + p.y*exp2f(p.x-mn);
    m = mn;
    int bio = __float_as_int(p.w);
    if (p.z > bv || (p.z == bv && bio < bi)){ bv = p.z; bi = bio; }
  }
  lse2[n] = m + log2f(s);
  hard[n] = bi;
  if (bi == codes[n]){ int p = atomicAdd(fixcnt, 1); fixlist[p] = n; }
}

// ---- rare fixup: argmax picked tgt -> rescan row excluding tgt (fp32) ----
__global__ __launch_bounds__(256) void k_fix(const ushort* __restrict__ zbf,
    const ushort* __restrict__ cbbf, const float* __restrict__ c2s,
    const int* __restrict__ codes, const int* __restrict__ fixcnt,
    const int* __restrict__ fixlist, int* __restrict__ hard){
  __shared__ float zr[CCD];
  __shared__ float rv[256]; __shared__ int ri[256];
  int nfix = *fixcnt;
  for (int j = blockIdx.x; j < nfix; j += gridDim.x){
    int n = fixlist[j];
    for (int i = threadIdx.x; i < CCD; i += 256) zr[i] = bf2f(zbf[(size_t)n*CCD + i]);
    __syncthreads();
    int tg = codes[n];
    float best = -3.0e38f; int bidx = 0;
    for (int k = threadIdx.x; k < KK; k += 256){
      if (k == tg) continue;
      const ushort* cr = cbbf + (size_t)k*CCD;
      float d = 0.f;
      for (int c = 0; c < CCD; ++c) d = fmaf(zr[c], bf2f(cr[c]), d);
      float val = fmaf(d, S20F, -c2s[k]);
      if (val > best){ best = val; bidx = k; }
    }
    rv[threadIdx.x] = best; ri[threadIdx.x] = bidx;
    __syncthreads();
    if (threadIdx.x == 0){
      float b = rv[0]; int bx = ri[0];
      for (int t = 1; t < 256; ++t)
        if (rv[t] > b || (rv[t] == b && ri[t] < bx)){ b = rv[t]; bx = ri[t]; }
      hard[n] = bx;
    }
    __syncthreads();
  }
}

// ---- finalize: triplet + direction + feature + exact fp32 logit[tgt] -> ce ----
__global__ __launch_bounds__(256) void k_final(const float* __restrict__ student,
    const float* __restrict__ teacher, const float* __restrict__ orig,
    const float* __restrict__ cb, const int* __restrict__ hard,
    const int* __restrict__ codes, const float* __restrict__ lse2,
    const float* __restrict__ c2s, float* __restrict__ accs){
  __shared__ float red[6][4][64];
  int tt = threadIdx.x & 63, cg = threadIdx.x >> 6;
  int n = blockIdx.x*64 + tt;
  float dp2=0,dn2=0,mm=0,dd=0,md=0,dt=0;
  bool ok = (n < NN);
  int tg = 0;
  if (ok){
    int hn = hard[n]; tg = codes[n];
    int b = n / TT, t = n - b*TT;
    size_t base = (size_t)b*CCD*TT + t;
    const float* ch = cb + (size_t)hn*CCD;
    const float* ct = cb + (size_t)tg*CCD;
    for (int c = cg*128; c < cg*128+128; ++c){
      float sv = student[base + (size_t)c*TT];
      float tv = teacher[base + (size_t)c*TT];
      float ov = orig[base + (size_t)c*TT];
      float cv = ch[c], wv = ct[c];
      float u = sv - tv; dp2 = fmaf(u,u,dp2);
      float v = tv - cv; dn2 = fmaf(v,v,dn2);
      float mv = sv - ov, dv = tv - ov;
      mm = fmaf(mv,mv,mm); dd = fmaf(dv,dv,dd); md = fmaf(mv,dv,md);
      dt = fmaf(sv, wv, dt);
    }
  }
  red[0][cg][tt]=dp2; red[1][cg][tt]=dn2; red[2][cg][tt]=mm;
  red[3][cg][tt]=dd;  red[4][cg][tt]=md;  red[5][cg][tt]=dt;
  __syncthreads();
  if (cg == 0){
    dp2 = red[0][0][tt]+red[0][1][tt]+red[0][2][tt]+red[0][3][tt];
    dn2 = red[1][0][tt]+red[1][1][tt]+red[1][2][tt]+red[1][3][tt];
    mm  = red[2][0][tt]+red[2][1][tt]+red[2][2][tt]+red[2][3][tt];
    dd  = red[3][0][tt]+red[3][1][tt]+red[3][2][tt]+red[3][3][tt];
    md  = red[4][0][tt]+red[4][1][tt]+red[4][2][tt]+red[4][3][tt];
    dt  = red[5][0][tt]+red[5][1][tt]+red[5][2][tt]+red[5][3][tt];
    float trip=0.f, dc=0.f, nv=0.f, ce=0.f;
    if (ok){
      float dpos = sqrtf(dp2), dneg = sqrtf(dn2);
      trip = fmaxf(dpos - dneg + 0.5f, 0.f);
      float mn = sqrtf(mm), dnn = sqrtf(dd);
      bool valid = (mn > 1e-6f) && (dnn > 1e-6f);
      float cosv = md / ((mn + 1e-8f)*(dnn + 1e-8f));
      if (valid){ dc = 1.f - cosv; nv = 1.f; }
      ce = lse2[n] - (fmaf(dt, S20F, -c2s[tg]));
    }
    for (int off=1; off<64; off<<=1){
      trip += __shfl_xor(trip,off);
      dc   += __shfl_xor(dc,off);
      nv   += __shfl_xor(nv,off);
      dp2  += __shfl_xor(dp2,off);
      ce   += __shfl_xor(ce,off);
    }
    if (tt == 0){
      atomicAdd(&accs[0], trip); atomicAdd(&accs[1], dc);
      atomicAdd(&accs[2], nv);   atomicAdd(&accs[3], dp2);
      atomicAdd(&accs[4], ce);
    }
  }
}

__global__ void k_total(const float* __restrict__ accs, float* __restrict__ out){
  float feat = accs[3] / 6144000.f;         // 8*512*1500
  float trip = accs[0] / (float)NN;
  float ce   = (accs[4] / (float)NN) * LN2F;
  float nv   = accs[2] < 1.f ? 1.f : accs[2];
  float dc   = accs[1] / nv;
  out[0] = 2.f*feat + trip + ce + dc;
}

extern "C" void kernel_launch(void* const* d_in, const int* in_sizes, int n_in,
                              void* d_out, int out_size, void* d_ws, size_t ws_size,
                              hipStream_t stream){
  const float* student = (const float*)d_in[0];
  const float* teacher = (const float*)d_in[1];
  const float* cb      = (const float*)d_in[2];
  const int*   codes   = (const int*)d_in[3];
  const float* orig    = (const float*)d_in[4];

  char* ws = (char*)d_ws;
  float4* pstate = (float4*)ws;                         // 4*12000*16  = 768000
  ushort* zbf    = (ushort*)(ws + 768000);              // 12000*512*2 = 12288000
  ushort* cbbf   = (ushort*)(ws + 13056000);            // 4096*512*2  = 4194304
  float*  c2s    = (float*)(ws + 17250304);             // 4096*4      = 16384
  float*  lse2   = (float*)(ws + 17266688);             // 48000
  int*    hard   = (int*)(ws + 17314688);               // 48000
  int*    fixlist= (int*)(ws + 17362688);               // 48000
  float*  accs   = (float*)(ws + 17410688);             // 8 floats
  int*    fixcnt = (int*)(ws + 17410720);               // 1 int

  hipMemsetAsync(ws + 17410688, 0, 64, stream);
  k_prep_cb<<<1024, 256, 0, stream>>>(cb, cbbf);
  k_c2<<<1024, 256, 0, stream>>>(cb, c2s);
  k_prep_z<<<dim3(24, 8, 8), 256, 0, stream>>>(student, zbf);
  k_dist<<<dim3(125, 4), 256, 0, stream>>>(zbf, cbbf, c2s, pstate);
  k_merge<<<47, 256, 0, stream>>>(pstate, codes, lse2, hard, fixlist, fixcnt);
  k_fix<<<64, 256, 0, stream>>>(zbf, cbbf, c2s, codes, fixcnt, fixlist, hard);
  k_final<<<188, 256, 0, stream>>>(student, teacher, orig, cb, hard, codes, lse2, c2s, accs);
  k_total<<<1, 1, 0, stream>>>(accs, (float*)d_out);
}

// Round 3
// 431.558 us; speedup vs baseline: 2.8435x; 1.0147x over previous
//
#include <hip/hip_runtime.h>
#include <math.h>

#define NN 12000
#define NP 12032            // padded rows (94*128)
#define CCD 512
#define KK 4096
#define TT 1500
#define S20F 28.853900817779268f   // 20*log2(e)
#define SC2F 14.426950408889634f   // 10*log2(e)
#define LN2F 0.6931471805599453f

typedef float f32x4 __attribute__((ext_vector_type(4)));
typedef __bf16 bf16x8 __attribute__((ext_vector_type(8)));

__device__ __forceinline__ ushort f2bf(float f){
  uint u = __float_as_uint(f);
  uint r = (u + 0x7fffu + ((u >> 16) & 1u)) >> 16;
  return (ushort)r;
}
__device__ __forceinline__ float bf2f(ushort u){
  return __uint_as_float(((uint)u) << 16);
}

typedef __attribute__((address_space(1))) const unsigned int g_u32;
typedef __attribute__((address_space(3))) unsigned int l_u32;
__device__ __forceinline__ void gload_lds16(const void* g, void* l){
  __builtin_amdgcn_global_load_lds((g_u32*)g, (l_u32*)l, 16, 0, 0);
}

// ---- student (B,C,T) f32 -> zbf[N][C] bf16 (tiled transpose) ----
__global__ __launch_bounds__(256) void k_prep_z(const float* __restrict__ src, ushort* __restrict__ dst){
  __shared__ float tile[64][65];
  int b = blockIdx.z, c0 = blockIdx.y*64, t0 = blockIdx.x*64;
  const float* sb = src + ((size_t)b*CCD + c0)*TT + t0;
  for (int i = 0; i < 16; ++i){
    int e = i*256 + threadIdx.x;
    int cl = e >> 6, tl = e & 63;
    if (t0 + tl < TT) tile[cl][tl] = sb[(size_t)cl*TT + tl];
  }
  __syncthreads();
  for (int i = 0; i < 16; ++i){
    int e = i*256 + threadIdx.x;
    int tl = e >> 6, cl = e & 63;
    if (t0 + tl < TT) dst[((size_t)b*TT + t0 + tl)*CCD + c0 + cl] = f2bf(tile[cl][tl]);
  }
}

// ---- codebook f32 -> pre-swizzled bf16 LDS-image layout ----
// image: [tile=32][131072 B]; within tile: code*1024 + cc*256 + slot*16,
// where slot = g_src ^ (code&7), g_src = 16B-chunk index (8 bf16) within cc-block.
__global__ __launch_bounds__(256) void k_prep_cb(const float* __restrict__ cb, ushort* __restrict__ cbsw){
  int id = blockIdx.x*256 + threadIdx.x;     // [0, 262144)
  int gs   = id & 15;
  int cc   = (id >> 4) & 3;
  int code = (id >> 6) & 127;
  int tile = id >> 13;
  int g = gs ^ (code & 7);
  const float* src = cb + (((size_t)(tile*128 + code))*CCD + cc*128 + g*8);
  float4 v0 = *(const float4*)src;
  float4 v1 = *(const float4*)(src + 4);
  uint4 o;
  o.x = (uint)f2bf(v0.x) | ((uint)f2bf(v0.y) << 16);
  o.y = (uint)f2bf(v0.z) | ((uint)f2bf(v0.w) << 16);
  o.z = (uint)f2bf(v1.x) | ((uint)f2bf(v1.y) << 16);
  o.w = (uint)f2bf(v1.z) | ((uint)f2bf(v1.w) << 16);
  ((uint4*)cbsw)[id] = o;
}

// ---- per-code scaled squared norms: c2s[k] = ||c_k||^2 * 10*log2e ----
__global__ __launch_bounds__(256) void k_c2(const float* __restrict__ cb, float* __restrict__ c2s){
  int k = blockIdx.x*4 + (threadIdx.x >> 6);
  int lane = threadIdx.x & 63;
  const float4* p = (const float4*)(cb + (size_t)k*CCD);
  float s = 0.f;
  for (int i = lane; i < CCD/4; i += 64){
    float4 v = p[i];
    s += v.x*v.x + v.y*v.y + v.z*v.z + v.w*v.w;
  }
  for (int off=1; off<64; off<<=1) s += __shfl_xor(s, off);
  if (lane == 0) c2s[k] = s * SC2F;
}

// ---- fused bf16-MFMA distance GEMM, A in registers, B in 128KB LDS tiles ----
// grid (8, 94): x = ksplit (512 codes), y = row block (128 rows)
__global__ __launch_bounds__(512, 2) void k_dist(const ushort* __restrict__ zbf,
    const ushort* __restrict__ cbsw, const float* __restrict__ c2s,
    float4* __restrict__ pstate){
  extern __shared__ char cs[];   // 131072 bytes
  int tid = threadIdx.x, w = tid >> 6, l = tid & 63;
  int lm = l & 15, k16 = l >> 4;
  int yk = blockIdx.x, xb = blockIdx.y;
  int n0 = xb * 128;
  int wr = w >> 1, wc = w & 1;

  // A fragments: 32 rows x 512 C per wave, 128 VGPRs/lane
  bf16x8 A0[16], A1[16];
  {
    const ushort* a0 = zbf + (size_t)(n0 + wr*32 + lm)*CCD + k16*8;
    const ushort* a1 = a0 + 16*CCD;
#pragma unroll
    for (int u = 0; u < 16; ++u){
      A0[u] = *(const bf16x8*)(a0 + u*32);
      A1[u] = *(const bf16x8*)(a1 + u*32);
    }
  }

  float m2[8], ss[8]; int bi[8];
#pragma unroll
  for (int i=0;i<8;++i){ m2[i]=-3.0e38f; ss[i]=0.f; bi[i]=0; }

  for (int it = 0; it < 4; ++it){
    const char* tb = (const char*)cbsw + ((size_t)(yk*4 + it))*131072;
    // stage full 128-code tile (128 KB), linear copy, each wave 16 KB
#pragma unroll
    for (int j = 0; j < 16; ++j)
      gload_lds16(tb + w*16384 + j*1024 + l*16, cs + w*16384 + j*1024);

    int colg0 = yk*512 + it*128 + wc*64 + lm;
    float c2r[4];
#pragma unroll
    for (int fj=0; fj<4; ++fj) c2r[fj] = c2s[colg0 + fj*16];

    f32x4 acc[2][4];
#pragma unroll
    for (int fi=0; fi<2; ++fi)
#pragma unroll
      for (int fj=0; fj<4; ++fj) acc[fi][fj] = (f32x4){0.f,0.f,0.f,0.f};

    __syncthreads();   // stage complete (drains vmcnt), A regs also ready
#pragma unroll
    for (int cc2 = 0; cc2 < 4; ++cc2){
#pragma unroll
      for (int ks = 0; ks < 4; ++ks){
        bf16x8 b[4];
#pragma unroll
        for (int fj=0; fj<4; ++fj){
          int code = wc*64 + fj*16 + lm;
          int byteoff = code*1024 + cc2*256 + ((((ks*4)+k16) ^ (code & 7)) << 4);
          b[fj] = *(const bf16x8*)(cs + byteoff);
        }
#pragma unroll
        for (int fj=0; fj<4; ++fj){
          acc[0][fj] = __builtin_amdgcn_mfma_f32_16x16x32_bf16(A0[cc2*4+ks], b[fj], acc[0][fj], 0,0,0);
          acc[1][fj] = __builtin_amdgcn_mfma_f32_16x16x32_bf16(A1[cc2*4+ks], b[fj], acc[1][fj], 0,0,0);
        }
      }
    }
    __syncthreads();   // all reads of cs done before next tile's stage

    // epilogue: online softmax + argmax(=max) over this tile's 4 col-frags
#pragma unroll
    for (int fi=0; fi<2; ++fi)
#pragma unroll
    for (int r=0; r<4; ++r){
      int i8 = fi*4 + r;
      float l2[4];
#pragma unroll
      for (int fj=0; fj<4; ++fj)
        l2[fj] = fmaf((fi ? acc[1][fj][r] : acc[0][fj][r]), S20F, -c2r[fj]);
      float tm = l2[0]; int ti = colg0;
#pragma unroll
      for (int fj=1; fj<4; ++fj) if (l2[fj] > tm){ tm = l2[fj]; ti = colg0 + fj*16; }
      if (tm > m2[i8]) bi[i8] = ti;
      float mn = fmaxf(m2[i8], tm);
      float s = ss[i8] * exp2f(m2[i8] - mn);
#pragma unroll
      for (int fj=0; fj<4; ++fj) s += exp2f(l2[fj] - mn);
      ss[i8] = s; m2[i8] = mn;
    }
  }

  // butterfly over the 16 lanes sharing each row
#pragma unroll
  for (int off = 1; off < 16; off <<= 1){
#pragma unroll
    for (int i=0; i<8; ++i){
      float mo = __shfl_xor(m2[i], off);
      float so = __shfl_xor(ss[i], off);
      int  bio = __shfl_xor(bi[i], off);
      if (mo > m2[i] || (mo == m2[i] && bio < bi[i])) bi[i] = bio;
      float mn = fmaxf(m2[i], mo);
      ss[i] = ss[i]*exp2f(m2[i]-mn) + so*exp2f(mo-mn);
      m2[i] = mn;
    }
  }
  if (lm == 0){
#pragma unroll
    for (int fi=0; fi<2; ++fi)
#pragma unroll
    for (int r=0; r<4; ++r){
      int i8 = fi*4 + r;
      int row = wr*32 + fi*16 + k16*4 + r;
      pstate[((size_t)(yk*2 + wc))*NP + n0 + row] =
          make_float4(m2[i8], ss[i8], __int_as_float(bi[i8]), 0.f);
    }
  }
}

// ---- merge the 16 partials per row ----
__global__ __launch_bounds__(256) void k_merge(const float4* __restrict__ pstate,
    const int* __restrict__ codes, float* __restrict__ lse2, int* __restrict__ hard,
    int* __restrict__ fixlist, int* __restrict__ fixcnt){
  int n = blockIdx.x*256 + threadIdx.x;
  if (n >= NN) return;
  float m=-3.0e38f, s=0.f; int bi=0x7fffffff;
  for (int sp = 0; sp < 16; ++sp){
    float4 p = pstate[(size_t)sp*NP + n];
    int pb = __float_as_int(p.z);
    if (p.x > m || (p.x == m && pb < bi)) bi = pb;
    float mn = fmaxf(m, p.x);
    s = s*exp2f(m - mn) + p.y*exp2f(p.x - mn);
    m = mn;
  }
  lse2[n] = m + log2f(s);
  hard[n] = bi;
  if (bi == codes[n]){ int p = atomicAdd(fixcnt, 1); fixlist[p] = n; }
}

// ---- rare fixup: argmax picked tgt -> rescan row excluding tgt ----
__global__ __launch_bounds__(256) void k_fix(const ushort* __restrict__ zbf,
    const float* __restrict__ cb, const float* __restrict__ c2s,
    const int* __restrict__ codes, const int* __restrict__ fixcnt,
    const int* __restrict__ fixlist, int* __restrict__ hard){
  __shared__ float zr[CCD];
  __shared__ float rv[256]; __shared__ int ri[256];
  int nfix = *fixcnt;
  for (int j = blockIdx.x; j < nfix; j += gridDim.x){
    int n = fixlist[j];
    for (int i = threadIdx.x; i < CCD; i += 256) zr[i] = bf2f(zbf[(size_t)n*CCD + i]);
    __syncthreads();
    int tg = codes[n];
    float best = -3.0e38f; int bidx = 0;
    for (int k = threadIdx.x; k < KK; k += 256){
      if (k == tg) continue;
      const float* cr = cb + (size_t)k*CCD;
      float d = 0.f;
      for (int c = 0; c < CCD; ++c) d = fmaf(zr[c], cr[c], d);
      float val = fmaf(d, S20F, -c2s[k]);
      if (val > best){ best = val; bidx = k; }
    }
    rv[threadIdx.x] = best; ri[threadIdx.x] = bidx;
    __syncthreads();
    if (threadIdx.x == 0){
      float b = rv[0]; int bx = ri[0];
      for (int t = 1; t < 256; ++t)
        if (rv[t] > b || (rv[t] == b && ri[t] < bx)){ b = rv[t]; bx = ri[t]; }
      hard[n] = bx;
    }
    __syncthreads();
  }
}

// ---- finalize: triplet + direction + feature + exact fp32 logit[tgt] -> ce ----
__global__ __launch_bounds__(256) void k_final(const float* __restrict__ student,
    const float* __restrict__ teacher, const float* __restrict__ orig,
    const float* __restrict__ cb, const int* __restrict__ hard,
    const int* __restrict__ codes, const float* __restrict__ lse2,
    const float* __restrict__ c2s, float* __restrict__ accs){
  __shared__ float red[6][4][64];
  int tt = threadIdx.x & 63, cg = threadIdx.x >> 6;
  int n = blockIdx.x*64 + tt;
  float dp2=0,dn2=0,mm=0,dd=0,md=0,dt=0;
  bool ok = (n < NN);
  int tg = 0;
  if (ok){
    int hn = hard[n]; tg = codes[n];
    int b = n / TT, t = n - b*TT;
    size_t base = (size_t)b*CCD*TT + t;
    const float* ch = cb + (size_t)hn*CCD;
    const float* ct = cb + (size_t)tg*CCD;
    for (int c = cg*128; c < cg*128+128; ++c){
      float sv = student[base + (size_t)c*TT];
      float tv = teacher[base + (size_t)c*TT];
      float ov = orig[base + (size_t)c*TT];
      float cv = ch[c], wv = ct[c];
      float u = sv - tv; dp2 = fmaf(u,u,dp2);
      float v = tv - cv; dn2 = fmaf(v,v,dn2);
      float mv = sv - ov, dv = tv - ov;
      mm = fmaf(mv,mv,mm); dd = fmaf(dv,dv,dd); md = fmaf(mv,dv,md);
      dt = fmaf(sv, wv, dt);
    }
  }
  red[0][cg][tt]=dp2; red[1][cg][tt]=dn2; red[2][cg][tt]=mm;
  red[3][cg][tt]=dd;  red[4][cg][tt]=md;  red[5][cg][tt]=dt;
  __syncthreads();
  if (cg == 0){
    dp2 = red[0][0][tt]+red[0][1][tt]+red[0][2][tt]+red[0][3][tt];
    dn2 = red[1][0][tt]+red[1][1][tt]+red[1][2][tt]+red[1][3][tt];
    mm  = red[2][0][tt]+red[2][1][tt]+red[2][2][tt]+red[2][3][tt];
    dd  = red[3][0][tt]+red[3][1][tt]+red[3][2][tt]+red[3][3][tt];
    md  = red[4][0][tt]+red[4][1][tt]+red[4][2][tt]+red[4][3][tt];
    dt  = red[5][0][tt]+red[5][1][tt]+red[5][2][tt]+red[5][3][tt];
    float trip=0.f, dc=0.f, nv=0.f, ce=0.f;
    if (ok){
      float dpos = sqrtf(dp2), dneg = sqrtf(dn2);
      trip = fmaxf(dpos - dneg + 0.5f, 0.f);
      float mn = sqrtf(mm), dnn = sqrtf(dd);
      bool valid = (mn > 1e-6f) && (dnn > 1e-6f);
      float cosv = md / ((mn + 1e-8f)*(dnn + 1e-8f));
      if (valid){ dc = 1.f - cosv; nv = 1.f; }
      ce = lse2[n] - (fmaf(dt, S20F, -c2s[tg]));
    }
    for (int off=1; off<64; off<<=1){
      trip += __shfl_xor(trip,off);
      dc   += __shfl_xor(dc,off);
      nv   += __shfl_xor(nv,off);
      dp2  += __shfl_xor(dp2,off);
      ce   += __shfl_xor(ce,off);
    }
    if (tt == 0){
      atomicAdd(&accs[0], trip); atomicAdd(&accs[1], dc);
      atomicAdd(&accs[2], nv);   atomicAdd(&accs[3], dp2);
      atomicAdd(&accs[4], ce);
    }
  }
}

__global__ void k_total(const float* __restrict__ accs, float* __restrict__ out){
  float feat = accs[3] / 6144000.f;         // 8*512*1500
  float trip = accs[0] / (float)NN;
  float ce   = (accs[4] / (float)NN) * LN2F;
  float nv   = accs[2] < 1.f ? 1.f : accs[2];
  float dc   = accs[1] / nv;
  out[0] = 2.f*feat + trip + ce + dc;
}

extern "C" void kernel_launch(void* const* d_in, const int* in_sizes, int n_in,
                              void* d_out, int out_size, void* d_ws, size_t ws_size,
                              hipStream_t stream){
  const float* student = (const float*)d_in[0];
  const float* teacher = (const float*)d_in[1];
  const float* cb      = (const float*)d_in[2];
  const int*   codes   = (const int*)d_in[3];
  const float* orig    = (const float*)d_in[4];

  char* ws = (char*)d_ws;
  ushort* zbf    = (ushort*)(ws);                  // 12032*512*2 = 12,320,768
  ushort* cbsw   = (ushort*)(ws + 12320768);       // 4,194,304
  float*  c2s    = (float*)(ws + 16515072);        // 16,384
  float4* pstate = (float4*)(ws + 16531456);       // 16*12032*16 = 3,080,192
  float*  lse2   = (float*)(ws + 19611648);        // 48,128
  int*    hard   = (int*)(ws + 19659776);          // 48,128
  int*    fixlist= (int*)(ws + 19707904);          // 48,128
  float*  accs   = (float*)(ws + 19756032);        // 8 floats
  int*    fixcnt = (int*)(ws + 19756064);          // 1 int

  hipMemsetAsync(ws + 19756032, 0, 64, stream);
  k_prep_cb<<<1024, 256, 0, stream>>>(cb, cbsw);
  k_c2<<<1024, 256, 0, stream>>>(cb, c2s);
  k_prep_z<<<dim3(24, 8, 8), 256, 0, stream>>>(student, zbf);
  k_dist<<<dim3(8, 94), 512, 131072, stream>>>(zbf, cbsw, c2s, pstate);
  k_merge<<<47, 256, 0, stream>>>(pstate, codes, lse2, hard, fixlist, fixcnt);
  k_fix<<<64, 256, 0, stream>>>(zbf, cb, c2s, codes, fixcnt, fixlist, hard);
  k_final<<<188, 256, 0, stream>>>(student, teacher, orig, cb, hard, codes, lse2, c2s, accs);
  k_total<<<1, 1, 0, stream>>>(accs, (float*)d_out);
}

// Round 4
// 377.916 us; speedup vs baseline: 3.2471x; 1.1419x over previous
//
#include <hip/hip_runtime.h>
#include <math.h>

#define NN 12000
#define NP 12032            // padded rows (94*128)
#define CCD 512
#define KK 4096
#define TT 1500
#define S20F 28.853900817779268f   // 20*log2(e)
#define SC2F 14.426950408889634f   // 10*log2(e)
#define LN2F 0.6931471805599453f

typedef float f32x4 __attribute__((ext_vector_type(4)));
typedef __bf16 bf16x8 __attribute__((ext_vector_type(8)));

__device__ __forceinline__ ushort f2bf(float f){
  uint u = __float_as_uint(f);
  uint r = (u + 0x7fffu + ((u >> 16) & 1u)) >> 16;
  return (ushort)r;
}
__device__ __forceinline__ float bf2f(ushort u){
  return __uint_as_float(((uint)u) << 16);
}

typedef __attribute__((address_space(1))) const unsigned int g_u32;
typedef __attribute__((address_space(3))) unsigned int l_u32;
__device__ __forceinline__ void gload_lds16(const void* g, void* l){
  __builtin_amdgcn_global_load_lds((g_u32*)g, (l_u32*)l, 16, 0, 0);
}

// ---- student (B,C,T) f32 -> zbf[N][C] bf16 (tiled transpose) ----
__global__ __launch_bounds__(256) void k_prep_z(const float* __restrict__ src, ushort* __restrict__ dst){
  __shared__ float tile[64][65];
  int b = blockIdx.z, c0 = blockIdx.y*64, t0 = blockIdx.x*64;
  const float* sb = src + ((size_t)b*CCD + c0)*TT + t0;
  for (int i = 0; i < 16; ++i){
    int e = i*256 + threadIdx.x;
    int cl = e >> 6, tl = e & 63;
    if (t0 + tl < TT) tile[cl][tl] = sb[(size_t)cl*TT + tl];
  }
  __syncthreads();
  for (int i = 0; i < 16; ++i){
    int e = i*256 + threadIdx.x;
    int tl = e >> 6, cl = e & 63;
    if (t0 + tl < TT) dst[((size_t)b*TT + t0 + tl)*CCD + c0 + cl] = f2bf(tile[cl][tl]);
  }
}

// ---- codebook f32 -> pre-swizzled bf16 LDS-image layout (64-code / 64KB tiles) ----
// image: [tile=64][65536 B]; within tile: code*1024 + cc*256 + slot*16,
// slot = g_src ^ (code&7), g_src = 16B-chunk (8 bf16) index within cc-block.
__global__ __launch_bounds__(256) void k_prep_cb(const float* __restrict__ cb, ushort* __restrict__ cbsw){
  int id = blockIdx.x*256 + threadIdx.x;     // [0, 262144) uint4 slots
  int gs   = id & 15;
  int cc   = (id >> 4) & 3;
  int code = (id >> 6) & 63;
  int tile = id >> 12;
  int g = gs ^ (code & 7);
  const float* src = cb + (((size_t)(tile*64 + code))*CCD + cc*128 + g*8);
  float4 v0 = *(const float4*)src;
  float4 v1 = *(const float4*)(src + 4);
  uint4 o;
  o.x = (uint)f2bf(v0.x) | ((uint)f2bf(v0.y) << 16);
  o.y = (uint)f2bf(v0.z) | ((uint)f2bf(v0.w) << 16);
  o.z = (uint)f2bf(v1.x) | ((uint)f2bf(v1.y) << 16);
  o.w = (uint)f2bf(v1.z) | ((uint)f2bf(v1.w) << 16);
  ((uint4*)cbsw)[id] = o;
}

// ---- per-code scaled squared norms: c2s[k] = ||c_k||^2 * 10*log2e ----
__global__ __launch_bounds__(256) void k_c2(const float* __restrict__ cb, float* __restrict__ c2s){
  int k = blockIdx.x*4 + (threadIdx.x >> 6);
  int lane = threadIdx.x & 63;
  const float4* p = (const float4*)(cb + (size_t)k*CCD);
  float s = 0.f;
  for (int i = lane; i < CCD/4; i += 64){
    float4 v = p[i];
    s += v.x*v.x + v.y*v.y + v.z*v.z + v.w*v.w;
  }
  for (int off=1; off<64; off<<=1) s += __shfl_xor(s, off);
  if (lane == 0) c2s[k] = s * SC2F;
}

// ---- fused bf16-MFMA distance GEMM, A in regs, B 64KB ping-pong LDS tiles ----
// grid (8, 94): x = ksplit (512 codes), y = row block (128 rows)
// bid%8 == ksplit -> each XCD keeps its 512KB codebook slice L2-resident.
__global__ __launch_bounds__(512, 2) void k_dist(const ushort* __restrict__ zbf,
    const ushort* __restrict__ cbsw, const float* __restrict__ c2s,
    const int* __restrict__ codes, float4* __restrict__ pstate){
  extern __shared__ char cs[];   // 2 x 65536
  int tid = threadIdx.x, w = tid >> 6, l = tid & 63;
  int lm = l & 15, k16 = l >> 4;
  int yk = blockIdx.x, xb = blockIdx.y;
  int n0 = xb * 128, kb = yk * 512;
  int wr = w >> 1, wc = w & 1;

  // A fragments: 32 rows x 512 C per wave (128 VGPRs)
  bf16x8 A0[16], A1[16];
  {
    const ushort* a0 = zbf + (size_t)(n0 + wr*32 + lm)*CCD + k16*8;
#pragma unroll
    for (int u = 0; u < 16; ++u){
      A0[u] = *(const bf16x8*)(a0 + u*32);
      A1[u] = *(const bf16x8*)(a0 + 16*CCD + u*32);
    }
  }
  // target codes for the 8 rows this lane owns (for argmax exclusion)
  int tgt[8];
#pragma unroll
  for (int fi=0; fi<2; ++fi)
#pragma unroll
    for (int r=0; r<4; ++r)
      tgt[fi*4+r] = codes[n0 + wr*32 + fi*16 + k16*4 + r];

  float m2[8], ss[8], bv[8]; int bi[8];
#pragma unroll
  for (int i=0;i<8;++i){ m2[i]=-3.0e38f; ss[i]=0.f; bv[i]=-3.0e38f; bi[i]=0x7fffffff; }

#define STAGE(tile, buf) { \
    const char* tb_ = (const char*)cbsw + ((size_t)(yk*8 + (tile)))*65536; \
    _Pragma("unroll") \
    for (int j_ = 0; j_ < 8; ++j_) \
      gload_lds16(tb_ + w*8192 + j_*1024 + l*16, (buf) + w*8192 + j_*1024); }

  STAGE(0, cs)
  __syncthreads();

#pragma unroll
  for (int t = 0; t < 8; ++t){
    char* cur = cs + (t & 1)*65536;
    char* nxt = cs + ((t + 1) & 1)*65536;
    if (t < 7) STAGE(t + 1, nxt)     // issue next tile's loads before compute

    int colg0 = kb + t*64 + wc*32 + lm;
    float c2r0 = c2s[colg0], c2r1 = c2s[colg0 + 16];

    f32x4 acc[2][2];
#pragma unroll
    for (int fi=0; fi<2; ++fi)
#pragma unroll
      for (int fj=0; fj<2; ++fj) acc[fi][fj] = (f32x4){0.f,0.f,0.f,0.f};

#pragma unroll
    for (int cc2 = 0; cc2 < 4; ++cc2){
#pragma unroll
      for (int ks = 0; ks < 4; ++ks){
        bf16x8 b0, b1;
        {
          int code0 = wc*32 + lm;
          int code1 = code0 + 16;
          b0 = *(const bf16x8*)(cur + code0*1024 + cc2*256 + ((((ks*4)+k16) ^ (code0 & 7)) << 4));
          b1 = *(const bf16x8*)(cur + code1*1024 + cc2*256 + ((((ks*4)+k16) ^ (code1 & 7)) << 4));
        }
        acc[0][0] = __builtin_amdgcn_mfma_f32_16x16x32_bf16(A0[cc2*4+ks], b0, acc[0][0], 0,0,0);
        acc[0][1] = __builtin_amdgcn_mfma_f32_16x16x32_bf16(A0[cc2*4+ks], b1, acc[0][1], 0,0,0);
        acc[1][0] = __builtin_amdgcn_mfma_f32_16x16x32_bf16(A1[cc2*4+ks], b0, acc[1][0], 0,0,0);
        acc[1][1] = __builtin_amdgcn_mfma_f32_16x16x32_bf16(A1[cc2*4+ks], b1, acc[1][1], 0,0,0);
      }
    }

    // epilogue: argmax (tgt-excluded) + online softmax (all cols)
#pragma unroll
    for (int fi=0; fi<2; ++fi)
#pragma unroll
    for (int r=0; r<4; ++r){
      int i8 = fi*4 + r;
      float v0 = fmaf(acc[fi][0][r], S20F, -c2r0);
      float v1 = fmaf(acc[fi][1][r], S20F, -c2r1);
      int c0 = colg0, c1 = colg0 + 16;
      if (c0 != tgt[i8] && v0 > bv[i8]){ bv[i8] = v0; bi[i8] = c0; }
      if (c1 != tgt[i8] && v1 > bv[i8]){ bv[i8] = v1; bi[i8] = c1; }
      float tm = fmaxf(v0, v1);
      float mn = fmaxf(m2[i8], tm);
      ss[i8] = ss[i8]*exp2f(m2[i8]-mn) + exp2f(v0-mn) + exp2f(v1-mn);
      m2[i8] = mn;
    }
    __syncthreads();   // next tile staged; all reads of cur done
  }
#undef STAGE

  // butterfly over the 16 lanes sharing each row
#pragma unroll
  for (int off = 1; off < 16; off <<= 1){
#pragma unroll
    for (int i=0; i<8; ++i){
      float mo = __shfl_xor(m2[i], off);
      float so = __shfl_xor(ss[i], off);
      float bvo = __shfl_xor(bv[i], off);
      int  bio = __shfl_xor(bi[i], off);
      if (bvo > bv[i] || (bvo == bv[i] && bio < bi[i])){ bv[i] = bvo; bi[i] = bio; }
      float mn = fmaxf(m2[i], mo);
      ss[i] = ss[i]*exp2f(m2[i]-mn) + so*exp2f(mo-mn);
      m2[i] = mn;
    }
  }
  if (lm == 0){
#pragma unroll
    for (int fi=0; fi<2; ++fi)
#pragma unroll
    for (int r=0; r<4; ++r){
      int i8 = fi*4 + r;
      int row = wr*32 + fi*16 + k16*4 + r;
      pstate[((size_t)(yk*2 + wc))*NP + n0 + row] =
          make_float4(m2[i8], ss[i8], bv[i8], __int_as_float(bi[i8]));
    }
  }
}

// ---- merge the 16 partials per row ----
__global__ __launch_bounds__(256) void k_merge(const float4* __restrict__ pstate,
    float* __restrict__ lse2, int* __restrict__ hard){
  int n = blockIdx.x*256 + threadIdx.x;
  if (n >= NN) return;
  float m=-3.0e38f, s=0.f, bv=-3.0e38f; int bi=0x7fffffff;
  for (int sp = 0; sp < 16; ++sp){
    float4 p = pstate[(size_t)sp*NP + n];
    int pb = __float_as_int(p.w);
    if (p.z > bv || (p.z == bv && pb < bi)){ bv = p.z; bi = pb; }
    float mn = fmaxf(m, p.x);
    s = s*exp2f(m - mn) + p.y*exp2f(p.x - mn);
    m = mn;
  }
  lse2[n] = m + log2f(s);
  hard[n] = bi;
}

// ---- finalize: triplet + direction + feature + exact fp32 logit[tgt] -> ce ----
__global__ __launch_bounds__(256) void k_final(const float* __restrict__ student,
    const float* __restrict__ teacher, const float* __restrict__ orig,
    const float* __restrict__ cb, const int* __restrict__ hard,
    const int* __restrict__ codes, const float* __restrict__ lse2,
    const float* __restrict__ c2s, float* __restrict__ accs){
  __shared__ float red[6][4][64];
  int tt = threadIdx.x & 63, cg = threadIdx.x >> 6;
  int n = blockIdx.x*64 + tt;
  float dp2=0,dn2=0,mm=0,dd=0,md=0,dt=0;
  bool ok = (n < NN);
  int tg = 0;
  if (ok){
    int hn = hard[n]; tg = codes[n];
    int b = n / TT, t = n - b*TT;
    size_t base = (size_t)b*CCD*TT + t;
    const float* ch = cb + (size_t)hn*CCD;
    const float* ct = cb + (size_t)tg*CCD;
    for (int c = cg*128; c < cg*128+128; ++c){
      float sv = student[base + (size_t)c*TT];
      float tv = teacher[base + (size_t)c*TT];
      float ov = orig[base + (size_t)c*TT];
      float cv = ch[c], wv = ct[c];
      float u = sv - tv; dp2 = fmaf(u,u,dp2);
      float v = tv - cv; dn2 = fmaf(v,v,dn2);
      float mv = sv - ov, dv = tv - ov;
      mm = fmaf(mv,mv,mm); dd = fmaf(dv,dv,dd); md = fmaf(mv,dv,md);
      dt = fmaf(sv, wv, dt);
    }
  }
  red[0][cg][tt]=dp2; red[1][cg][tt]=dn2; red[2][cg][tt]=mm;
  red[3][cg][tt]=dd;  red[4][cg][tt]=md;  red[5][cg][tt]=dt;
  __syncthreads();
  if (cg == 0){
    dp2 = red[0][0][tt]+red[0][1][tt]+red[0][2][tt]+red[0][3][tt];
    dn2 = red[1][0][tt]+red[1][1][tt]+red[1][2][tt]+red[1][3][tt];
    mm  = red[2][0][tt]+red[2][1][tt]+red[2][2][tt]+red[2][3][tt];
    dd  = red[3][0][tt]+red[3][1][tt]+red[3][2][tt]+red[3][3][tt];
    md  = red[4][0][tt]+red[4][1][tt]+red[4][2][tt]+red[4][3][tt];
    dt  = red[5][0][tt]+red[5][1][tt]+red[5][2][tt]+red[5][3][tt];
    float trip=0.f, dc=0.f, nv=0.f, ce=0.f;
    if (ok){
      float dpos = sqrtf(dp2), dneg = sqrtf(dn2);
      trip = fmaxf(dpos - dneg + 0.5f, 0.f);
      float mn = sqrtf(mm), dnn = sqrtf(dd);
      bool valid = (mn > 1e-6f) && (dnn > 1e-6f);
      float cosv = md / ((mn + 1e-8f)*(dnn + 1e-8f));
      if (valid){ dc = 1.f - cosv; nv = 1.f; }
      ce = lse2[n] - (fmaf(dt, S20F, -c2s[tg]));
    }
    for (int off=1; off<64; off<<=1){
      trip += __shfl_xor(trip,off);
      dc   += __shfl_xor(dc,off);
      nv   += __shfl_xor(nv,off);
      dp2  += __shfl_xor(dp2,off);
      ce   += __shfl_xor(ce,off);
    }
    if (tt == 0){
      atomicAdd(&accs[0], trip); atomicAdd(&accs[1], dc);
      atomicAdd(&accs[2], nv);   atomicAdd(&accs[3], dp2);
      atomicAdd(&accs[4], ce);
    }
  }
}

__global__ void k_total(const float* __restrict__ accs, float* __restrict__ out){
  float feat = accs[3] / 6144000.f;         // 8*512*1500
  float trip = accs[0] / (float)NN;
  float ce   = (accs[4] / (float)NN) * LN2F;
  float nv   = accs[2] < 1.f ? 1.f : accs[2];
  float dc   = accs[1] / nv;
  out[0] = 2.f*feat + trip + ce + dc;
}

extern "C" void kernel_launch(void* const* d_in, const int* in_sizes, int n_in,
                              void* d_out, int out_size, void* d_ws, size_t ws_size,
                              hipStream_t stream){
  const float* student = (const float*)d_in[0];
  const float* teacher = (const float*)d_in[1];
  const float* cb      = (const float*)d_in[2];
  const int*   codes   = (const int*)d_in[3];
  const float* orig    = (const float*)d_in[4];

  char* ws = (char*)d_ws;
  ushort* zbf    = (ushort*)(ws);                  // 12032*512*2 = 12,320,768
  ushort* cbsw   = (ushort*)(ws + 12320768);       // 4,194,304
  float*  c2s    = (float*)(ws + 16515072);        // 16,384
  float4* pstate = (float4*)(ws + 16531456);       // 16*12032*16 = 3,080,192
  float*  lse2   = (float*)(ws + 19611648);        // 48,128
  int*    hard   = (int*)(ws + 19659776);          // 48,128
  float*  accs   = (float*)(ws + 19707904);        // 8 floats
  hipMemsetAsync(ws + 19707904, 0, 64, stream);
  k_prep_cb<<<1024, 256, 0, stream>>>(cb, cbsw);
  k_c2<<<1024, 256, 0, stream>>>(cb, c2s);
  k_prep_z<<<dim3(24, 8, 8), 256, 0, stream>>>(student, zbf);
  k_dist<<<dim3(8, 94), 512, 131072, stream>>>(zbf, cbsw, c2s, codes, pstate);
  k_merge<<<47, 256, 0, stream>>>(pstate, lse2, hard);
  k_final<<<188, 256, 0, stream>>>(student, teacher, orig, cb, hard, codes, lse2, c2s, accs);
  k_total<<<1, 1, 0, stream>>>(accs, (float*)d_out);
}

// Round 5
// 328.601 us; speedup vs baseline: 3.7344x; 1.1501x over previous
//
#include <hip/hip_runtime.h>
#include <math.h>

#define NN 12000
#define NP 12032            // padded rows (94*128)
#define CCD 512
#define KK 4096
#define TT 1500
#define S20F 28.853900817779268f   // 20*log2(e)
#define SC2F 14.426950408889634f   // 10*log2(e)
#define LN2F 0.6931471805599453f

typedef float f32x4 __attribute__((ext_vector_type(4)));
typedef __bf16 bf16x8 __attribute__((ext_vector_type(8)));

__device__ __forceinline__ ushort f2bf(float f){
  uint u = __float_as_uint(f);
  uint r = (u + 0x7fffu + ((u >> 16) & 1u)) >> 16;
  return (ushort)r;
}
__device__ __forceinline__ float bf2f(ushort u){
  return __uint_as_float(((uint)u) << 16);
}

typedef __attribute__((address_space(1))) const unsigned int g_u32;
typedef __attribute__((address_space(3))) unsigned int l_u32;
__device__ __forceinline__ void gload_lds16(const void* g, void* l){
  __builtin_amdgcn_global_load_lds((g_u32*)g, (l_u32*)l, 16, 0, 0);
}

// ---- student (B,C,T) f32 -> zbf[N][C] bf16 (tiled transpose) ----
__global__ __launch_bounds__(256) void k_prep_z(const float* __restrict__ src, ushort* __restrict__ dst){
  __shared__ float tile[64][65];
  int b = blockIdx.z, c0 = blockIdx.y*64, t0 = blockIdx.x*64;
  const float* sb = src + ((size_t)b*CCD + c0)*TT + t0;
  for (int i = 0; i < 16; ++i){
    int e = i*256 + threadIdx.x;
    int cl = e >> 6, tl = e & 63;
    if (t0 + tl < TT) tile[cl][tl] = sb[(size_t)cl*TT + tl];
  }
  __syncthreads();
  for (int i = 0; i < 16; ++i){
    int e = i*256 + threadIdx.x;
    int tl = e >> 6, cl = e & 63;
    if (t0 + tl < TT) dst[((size_t)b*TT + t0 + tl)*CCD + c0 + cl] = f2bf(tile[cl][tl]);
  }
}

// ---- codebook f32 -> pre-swizzled bf16 LDS-image layout (64-code / 64KB tiles) ----
// image: [tile=64][65536 B]; within tile: code*1024 + cc*256 + slot*16,
// slot = g_src ^ (code&7), g_src = 16B-chunk (8 bf16) index within cc-block.
__global__ __launch_bounds__(256) void k_prep_cb(const float* __restrict__ cb, ushort* __restrict__ cbsw){
  int id = blockIdx.x*256 + threadIdx.x;     // [0, 262144) uint4 slots
  int gs   = id & 15;
  int cc   = (id >> 4) & 3;
  int code = (id >> 6) & 63;
  int tile = id >> 12;
  int g = gs ^ (code & 7);
  const float* src = cb + (((size_t)(tile*64 + code))*CCD + cc*128 + g*8);
  float4 v0 = *(const float4*)src;
  float4 v1 = *(const float4*)(src + 4);
  uint4 o;
  o.x = (uint)f2bf(v0.x) | ((uint)f2bf(v0.y) << 16);
  o.y = (uint)f2bf(v0.z) | ((uint)f2bf(v0.w) << 16);
  o.z = (uint)f2bf(v1.x) | ((uint)f2bf(v1.y) << 16);
  o.w = (uint)f2bf(v1.z) | ((uint)f2bf(v1.w) << 16);
  ((uint4*)cbsw)[id] = o;
}

// ---- per-code scaled squared norms: c2s[k] = ||c_k||^2 * 10*log2e ----
__global__ __launch_bounds__(256) void k_c2(const float* __restrict__ cb, float* __restrict__ c2s){
  int k = blockIdx.x*4 + (threadIdx.x >> 6);
  int lane = threadIdx.x & 63;
  const float4* p = (const float4*)(cb + (size_t)k*CCD);
  float s = 0.f;
  for (int i = lane; i < CCD/4; i += 64){
    float4 v = p[i];
    s += v.x*v.x + v.y*v.y + v.z*v.z + v.w*v.w;
  }
  for (int off=1; off<64; off<<=1) s += __shfl_xor(s, off);
  if (lane == 0) c2s[k] = s * SC2F;
}

// ---- fused bf16-MFMA distance GEMM, A in regs, B 64KB ping-pong LDS tiles ----
// grid (8, 94): x = ksplit (512 codes), y = row block (128 rows)
// bid%8 == ksplit -> each XCD keeps its 512KB codebook slice L2-resident.
// amdgpu_waves_per_eu(2): cap regalloc at 256 VGPR (kernel needs ~210) — the
// R4 __launch_bounds__(512,2) form capped at 128 and spilled 337MB to scratch.
__global__ __launch_bounds__(512) __attribute__((amdgpu_waves_per_eu(2)))
void k_dist(const ushort* __restrict__ zbf,
    const ushort* __restrict__ cbsw, const float* __restrict__ c2s,
    const int* __restrict__ codes, float4* __restrict__ pstate){
  extern __shared__ char cs[];   // 2 x 65536
  int tid = threadIdx.x, w = tid >> 6, l = tid & 63;
  int lm = l & 15, k16 = l >> 4;
  int yk = blockIdx.x, xb = blockIdx.y;
  int n0 = xb * 128, kb = yk * 512;
  int wr = w >> 1, wc = w & 1;

  // A fragments: 32 rows x 512 C per wave (128 VGPRs)
  bf16x8 A0[16], A1[16];
  {
    const ushort* a0 = zbf + (size_t)(n0 + wr*32 + lm)*CCD + k16*8;
#pragma unroll
    for (int u = 0; u < 16; ++u){
      A0[u] = *(const bf16x8*)(a0 + u*32);
      A1[u] = *(const bf16x8*)(a0 + 16*CCD + u*32);
    }
  }
  // target codes for the 8 rows this lane owns (for argmax exclusion)
  int tgt[8];
#pragma unroll
  for (int fi=0; fi<2; ++fi)
#pragma unroll
    for (int r=0; r<4; ++r)
      tgt[fi*4+r] = codes[n0 + wr*32 + fi*16 + k16*4 + r];

  float m2[8], ss[8], bv[8]; int bi[8];
#pragma unroll
  for (int i=0;i<8;++i){ m2[i]=-3.0e38f; ss[i]=0.f; bv[i]=-3.0e38f; bi[i]=0x7fffffff; }

#define STAGE(tile, buf) { \
    const char* tb_ = (const char*)cbsw + ((size_t)(yk*8 + (tile)))*65536; \
    _Pragma("unroll") \
    for (int j_ = 0; j_ < 8; ++j_) \
      gload_lds16(tb_ + w*8192 + j_*1024 + l*16, (buf) + w*8192 + j_*1024); }

  STAGE(0, cs)
  __syncthreads();

#pragma unroll
  for (int t = 0; t < 8; ++t){
    char* cur = cs + (t & 1)*65536;
    char* nxt = cs + ((t + 1) & 1)*65536;
    if (t < 7) STAGE(t + 1, nxt)     // issue next tile's loads before compute

    int colg0 = kb + t*64 + wc*32 + lm;
    float c2r0 = c2s[colg0], c2r1 = c2s[colg0 + 16];

    f32x4 acc[2][2];
#pragma unroll
    for (int fi=0; fi<2; ++fi)
#pragma unroll
      for (int fj=0; fj<2; ++fj) acc[fi][fj] = (f32x4){0.f,0.f,0.f,0.f};

#pragma unroll
    for (int cc2 = 0; cc2 < 4; ++cc2){
#pragma unroll
      for (int ks = 0; ks < 4; ++ks){
        bf16x8 b0, b1;
        {
          int code0 = wc*32 + lm;
          int code1 = code0 + 16;
          b0 = *(const bf16x8*)(cur + code0*1024 + cc2*256 + ((((ks*4)+k16) ^ (code0 & 7)) << 4));
          b1 = *(const bf16x8*)(cur + code1*1024 + cc2*256 + ((((ks*4)+k16) ^ (code1 & 7)) << 4));
        }
        acc[0][0] = __builtin_amdgcn_mfma_f32_16x16x32_bf16(A0[cc2*4+ks], b0, acc[0][0], 0,0,0);
        acc[0][1] = __builtin_amdgcn_mfma_f32_16x16x32_bf16(A0[cc2*4+ks], b1, acc[0][1], 0,0,0);
        acc[1][0] = __builtin_amdgcn_mfma_f32_16x16x32_bf16(A1[cc2*4+ks], b0, acc[1][0], 0,0,0);
        acc[1][1] = __builtin_amdgcn_mfma_f32_16x16x32_bf16(A1[cc2*4+ks], b1, acc[1][1], 0,0,0);
      }
    }

    // epilogue: argmax (tgt-excluded) + online softmax (all cols)
#pragma unroll
    for (int fi=0; fi<2; ++fi)
#pragma unroll
    for (int r=0; r<4; ++r){
      int i8 = fi*4 + r;
      float v0 = fmaf(acc[fi][0][r], S20F, -c2r0);
      float v1 = fmaf(acc[fi][1][r], S20F, -c2r1);
      int c0 = colg0, c1 = colg0 + 16;
      if (c0 != tgt[i8] && v0 > bv[i8]){ bv[i8] = v0; bi[i8] = c0; }
      if (c1 != tgt[i8] && v1 > bv[i8]){ bv[i8] = v1; bi[i8] = c1; }
      float tm = fmaxf(v0, v1);
      float mn = fmaxf(m2[i8], tm);
      ss[i8] = ss[i8]*exp2f(m2[i8]-mn) + exp2f(v0-mn) + exp2f(v1-mn);
      m2[i8] = mn;
    }
    __syncthreads();   // next tile staged; all reads of cur done
  }
#undef STAGE

  // butterfly over the 16 lanes sharing each row
#pragma unroll
  for (int off = 1; off < 16; off <<= 1){
#pragma unroll
    for (int i=0; i<8; ++i){
      float mo = __shfl_xor(m2[i], off);
      float so = __shfl_xor(ss[i], off);
      float bvo = __shfl_xor(bv[i], off);
      int  bio = __shfl_xor(bi[i], off);
      if (bvo > bv[i] || (bvo == bv[i] && bio < bi[i])){ bv[i] = bvo; bi[i] = bio; }
      float mn = fmaxf(m2[i], mo);
      ss[i] = ss[i]*exp2f(m2[i]-mn) + so*exp2f(mo-mn);
      m2[i] = mn;
    }
  }
  if (lm == 0){
#pragma unroll
    for (int fi=0; fi<2; ++fi)
#pragma unroll
    for (int r=0; r<4; ++r){
      int i8 = fi*4 + r;
      int row = wr*32 + fi*16 + k16*4 + r;
      pstate[((size_t)(yk*2 + wc))*NP + n0 + row] =
          make_float4(m2[i8], ss[i8], bv[i8], __int_as_float(bi[i8]));
    }
  }
}

// ---- merge the 16 partials per row ----
__global__ __launch_bounds__(256) void k_merge(const float4* __restrict__ pstate,
    float* __restrict__ lse2, int* __restrict__ hard){
  int n = blockIdx.x*256 + threadIdx.x;
  if (n >= NN) return;
  float m=-3.0e38f, s=0.f, bv=-3.0e38f; int bi=0x7fffffff;
  for (int sp = 0; sp < 16; ++sp){
    float4 p = pstate[(size_t)sp*NP + n];
    int pb = __float_as_int(p.w);
    if (p.z > bv || (p.z == bv && pb < bi)){ bv = p.z; bi = pb; }
    float mn = fmaxf(m, p.x);
    s = s*exp2f(m - mn) + p.y*exp2f(p.x - mn);
    m = mn;
  }
  lse2[n] = m + log2f(s);
  hard[n] = bi;
}

// ---- finalize: triplet + direction + feature + exact fp32 logit[tgt] -> ce ----
__global__ __launch_bounds__(256) void k_final(const float* __restrict__ student,
    const float* __restrict__ teacher, const float* __restrict__ orig,
    const float* __restrict__ cb, const int* __restrict__ hard,
    const int* __restrict__ codes, const float* __restrict__ lse2,
    const float* __restrict__ c2s, float* __restrict__ accs){
  __shared__ float red[6][4][64];
  int tt = threadIdx.x & 63, cg = threadIdx.x >> 6;
  int n = blockIdx.x*64 + tt;
  float dp2=0,dn2=0,mm=0,dd=0,md=0,dt=0;
  bool ok = (n < NN);
  int tg = 0;
  if (ok){
    int hn = hard[n]; tg = codes[n];
    int b = n / TT, t = n - b*TT;
    size_t base = (size_t)b*CCD*TT + t;
    const float* ch = cb + (size_t)hn*CCD;
    const float* ct = cb + (size_t)tg*CCD;
    for (int c = cg*128; c < cg*128+128; ++c){
      float sv = student[base + (size_t)c*TT];
      float tv = teacher[base + (size_t)c*TT];
      float ov = orig[base + (size_t)c*TT];
      float cv = ch[c], wv = ct[c];
      float u = sv - tv; dp2 = fmaf(u,u,dp2);
      float v = tv - cv; dn2 = fmaf(v,v,dn2);
      float mv = sv - ov, dv = tv - ov;
      mm = fmaf(mv,mv,mm); dd = fmaf(dv,dv,dd); md = fmaf(mv,dv,md);
      dt = fmaf(sv, wv, dt);
    }
  }
  red[0][cg][tt]=dp2; red[1][cg][tt]=dn2; red[2][cg][tt]=mm;
  red[3][cg][tt]=dd;  red[4][cg][tt]=md;  red[5][cg][tt]=dt;
  __syncthreads();
  if (cg == 0){
    dp2 = red[0][0][tt]+red[0][1][tt]+red[0][2][tt]+red[0][3][tt];
    dn2 = red[1][0][tt]+red[1][1][tt]+red[1][2][tt]+red[1][3][tt];
    mm  = red[2][0][tt]+red[2][1][tt]+red[2][2][tt]+red[2][3][tt];
    dd  = red[3][0][tt]+red[3][1][tt]+red[3][2][tt]+red[3][3][tt];
    md  = red[4][0][tt]+red[4][1][tt]+red[4][2][tt]+red[4][3][tt];
    dt  = red[5][0][tt]+red[5][1][tt]+red[5][2][tt]+red[5][3][tt];
    float trip=0.f, dc=0.f, nv=0.f, ce=0.f;
    if (ok){
      float dpos = sqrtf(dp2), dneg = sqrtf(dn2);
      trip = fmaxf(dpos - dneg + 0.5f, 0.f);
      float mn = sqrtf(mm), dnn = sqrtf(dd);
      bool valid = (mn > 1e-6f) && (dnn > 1e-6f);
      float cosv = md / ((mn + 1e-8f)*(dnn + 1e-8f));
      if (valid){ dc = 1.f - cosv; nv = 1.f; }
      ce = lse2[n] - (fmaf(dt, S20F, -c2s[tg]));
    }
    for (int off=1; off<64; off<<=1){
      trip += __shfl_xor(trip,off);
      dc   += __shfl_xor(dc,off);
      nv   += __shfl_xor(nv,off);
      dp2  += __shfl_xor(dp2,off);
      ce   += __shfl_xor(ce,off);
    }
    if (tt == 0){
      atomicAdd(&accs[0], trip); atomicAdd(&accs[1], dc);
      atomicAdd(&accs[2], nv);   atomicAdd(&accs[3], dp2);
      atomicAdd(&accs[4], ce);
    }
  }
}

__global__ void k_total(const float* __restrict__ accs, float* __restrict__ out){
  float feat = accs[3] / 6144000.f;         // 8*512*1500
  float trip = accs[0] / (float)NN;
  float ce   = (accs[4] / (float)NN) * LN2F;
  float nv   = accs[2] < 1.f ? 1.f : accs[2];
  float dc   = accs[1] / nv;
  out[0] = 2.f*feat + trip + ce + dc;
}

extern "C" void kernel_launch(void* const* d_in, const int* in_sizes, int n_in,
                              void* d_out, int out_size, void* d_ws, size_t ws_size,
                              hipStream_t stream){
  const float* student = (const float*)d_in[0];
  const float* teacher = (const float*)d_in[1];
  const float* cb      = (const float*)d_in[2];
  const int*   codes   = (const int*)d_in[3];
  const float* orig    = (const float*)d_in[4];

  char* ws = (char*)d_ws;
  ushort* zbf    = (ushort*)(ws);                  // 12032*512*2 = 12,320,768
  ushort* cbsw   = (ushort*)(ws + 12320768);       // 4,194,304
  float*  c2s    = (float*)(ws + 16515072);        // 16,384
  float4* pstate = (float4*)(ws + 16531456);       // 16*12032*16 = 3,080,192
  float*  lse2   = (float*)(ws + 19611648);        // 48,128
  int*    hard   = (int*)(ws + 19659776);          // 48,128
  float*  accs   = (float*)(ws + 19707904);        // 8 floats
  hipMemsetAsync(ws + 19707904, 0, 64, stream);
  k_prep_cb<<<1024, 256, 0, stream>>>(cb, cbsw);
  k_c2<<<1024, 256, 0, stream>>>(cb, c2s);
  k_prep_z<<<dim3(24, 8, 8), 256, 0, stream>>>(student, zbf);
  k_dist<<<dim3(8, 94), 512, 131072, stream>>>(zbf, cbsw, c2s, codes, pstate);
  k_merge<<<47, 256, 0, stream>>>(pstate, lse2, hard);
  k_final<<<188, 256, 0, stream>>>(student, teacher, orig, cb, hard, codes, lse2, c2s, accs);
  k_total<<<1, 1, 0, stream>>>(accs, (float*)d_out);
}